// Round 1
// baseline (195.477 us; speedup 1.0000x reference)
//
#include <hip/hip_runtime.h>
#include <hip/hip_bf16.h>

typedef __attribute__((ext_vector_type(8))) short short8;
typedef __attribute__((ext_vector_type(4))) float float4v;

#define LOG2E 1.44269504088896340736f

__device__ __forceinline__ unsigned short f2bf(float f) {
    unsigned int u = __float_as_uint(f);
    unsigned int r = (u + 0x7fffu + ((u >> 16) & 1u)) >> 16;  // RNE
    return (unsigned short)r;
}

// ---------------------------------------------------------------------------
// Kernel 1: convert Wk|Wq|Wv (fp32) -> combined bf16 Wb[192][1024]
// ---------------------------------------------------------------------------
__global__ void wconv_kernel(const float* __restrict__ Wk, const float* __restrict__ Wq,
                             const float* __restrict__ Wv, unsigned short* __restrict__ Wb) {
    int i = blockIdx.x * 256 + threadIdx.x;
    if (i >= 192 * 1024) return;
    float v;
    if (i < 65536)       v = Wk[i];
    else if (i < 131072) v = Wq[i - 65536];
    else                 v = Wv[i - 131072];
    Wb[i] = f2bf(v);
}

// ---------------------------------------------------------------------------
// Kernel 2: projection GEMM — round-12: BARRIER-FREE register GEMM.
// R11 counters: MfmaUtil 5.3%, VALUBusy 11%, HBM 13%, Occupancy 13-16% ->
// latency-bound. Grid 512 = 2 blocks/CU (2 waves/SIMD) and the per-iteration
// __syncthreads() drained vmcnt(0) (pipeline depth 1 vs ~900cy HBM latency).
// Fix: Wb (384 KB) is L2-resident -> load B fragments (short8, 16B/lane,
// 64B-coalesced per 16-lane group) DIRECTLY from global; no LDS, no barriers.
// Row tile 32 -> 16 doubles grid to 1024 (4 blocks/CU = 16 waves/CU); each
// of the 4 waves owns 48 W-rows (3 n-tiles). 2-deep A-register prefetch
// (~480cy cover). __launch_bounds__(256,4) caps VGPR at 128 for 4 waves/EU.
// ---------------------------------------------------------------------------
__global__ __launch_bounds__(256, 4) void proj_kernel(
    const float* __restrict__ x, const unsigned short* __restrict__ Wb,
    unsigned short* __restrict__ qs, unsigned short* __restrict__ ks,
    unsigned short* __restrict__ vT) {
    const int tid  = threadIdx.x;
    const int lane = tid & 63;
    const int wave = tid >> 6;   // 0..3 -> W-row block of 48 (3 n-tiles of 16)
    const int quad = lane >> 4;
    const int l16  = lane & 15;
    const int t0   = blockIdx.x * 16;

    const float* xr = x + (size_t)(t0 + l16) * 1024;

    // B row base pointers for this wave's 3 n-tiles; quad*8 = K-subchunk.
    const unsigned short* brow0 = Wb + (size_t)((wave * 3 + 0) * 16 + l16) * 1024 + quad * 8;
    const unsigned short* brow1 = brow0 + 16 * 1024;
    const unsigned short* brow2 = brow0 + 32 * 1024;

    float4v acc0 = (float4v){0.f, 0.f, 0.f, 0.f};
    float4v acc1 = (float4v){0.f, 0.f, 0.f, 0.f};
    float4v acc2 = (float4v){0.f, 0.f, 0.f, 0.f};

    // 2-deep A prefetch: a0 = tile kt, a1 = tile kt+1, an = tile kt+2
    float4v a0[4], a1[4];
    a0[0] = *(const float4v*)(xr + quad * 8);
    a0[1] = *(const float4v*)(xr + quad * 8 + 4);
    a0[2] = *(const float4v*)(xr + 32 + quad * 8);
    a0[3] = *(const float4v*)(xr + 32 + quad * 8 + 4);
    a1[0] = *(const float4v*)(xr + 64 + quad * 8);
    a1[1] = *(const float4v*)(xr + 64 + quad * 8 + 4);
    a1[2] = *(const float4v*)(xr + 96 + quad * 8);
    a1[3] = *(const float4v*)(xr + 96 + quad * 8 + 4);

#pragma unroll 2
    for (int kt = 0; kt < 16; kt++) {
        const int kn = ((kt + 2) & 15) * 64;  // wraps at end: redundant, harmless
        float4v an[4];
        an[0] = *(const float4v*)(xr + kn + quad * 8);
        an[1] = *(const float4v*)(xr + kn + quad * 8 + 4);
        an[2] = *(const float4v*)(xr + kn + 32 + quad * 8);
        an[3] = *(const float4v*)(xr + kn + 32 + quad * 8 + 4);

        // B fragments straight from global (L2-resident). kc=1 -> +32 ushorts.
        const unsigned short* b0 = brow0 + kt * 64;
        const unsigned short* b1 = brow1 + kt * 64;
        const unsigned short* b2 = brow2 + kt * 64;
        const short8 bf00 = *(const short8*)(b0);
        const short8 bf01 = *(const short8*)(b1);
        const short8 bf02 = *(const short8*)(b2);
        const short8 bf10 = *(const short8*)(b0 + 32);
        const short8 bf11 = *(const short8*)(b1 + 32);
        const short8 bf12 = *(const short8*)(b2 + 32);

        {
            short8 af;
#pragma unroll
            for (int j = 0; j < 4; j++) af[j] = (short)f2bf(a0[0][j]);
#pragma unroll
            for (int j = 0; j < 4; j++) af[4 + j] = (short)f2bf(a0[1][j]);
            acc0 = __builtin_amdgcn_mfma_f32_16x16x32_bf16(af, bf00, acc0, 0, 0, 0);
            acc1 = __builtin_amdgcn_mfma_f32_16x16x32_bf16(af, bf01, acc1, 0, 0, 0);
            acc2 = __builtin_amdgcn_mfma_f32_16x16x32_bf16(af, bf02, acc2, 0, 0, 0);
        }
        {
            short8 af;
#pragma unroll
            for (int j = 0; j < 4; j++) af[j] = (short)f2bf(a0[2][j]);
#pragma unroll
            for (int j = 0; j < 4; j++) af[4 + j] = (short)f2bf(a0[3][j]);
            acc0 = __builtin_amdgcn_mfma_f32_16x16x32_bf16(af, bf10, acc0, 0, 0, 0);
            acc1 = __builtin_amdgcn_mfma_f32_16x16x32_bf16(af, bf11, acc1, 0, 0, 0);
            acc2 = __builtin_amdgcn_mfma_f32_16x16x32_bf16(af, bf12, acc2, 0, 0, 0);
        }
#pragma unroll
        for (int i = 0; i < 4; i++) { a0[i] = a1[i]; a1[i] = an[i]; }
    }

    // Epilogue. C layout: row = quad*4 + r (A-row within tile), col = l16.
    // W-row tile mt = wave*3+n: 0-3 -> ks, 4-7 -> qs (x0.125), 8-11 -> vT.
    const int rowD = t0 + quad * 4;
    const float4v accs[3] = {acc0, acc1, acc2};
#pragma unroll
    for (int n = 0; n < 3; n++) {
        const int mt = wave * 3 + n;
#pragma unroll
        for (int r = 0; r < 4; r++) {
            const int t = rowD + r;
            const float val = accs[n][r];
            if (mt < 4) {
                ks[(size_t)t * 64 + mt * 16 + l16] = f2bf(val);
            } else if (mt < 8) {
                qs[(size_t)t * 64 + (mt - 4) * 16 + l16] = f2bf(val * 0.125f);
            } else {
                const int b = t >> 11, tt = t & 2047;
                vT[(size_t)b * 131072 + (size_t)((mt - 8) * 16 + l16) * 2048 + tt] = f2bf(val);
            }
        }
    }
}

// ---------------------------------------------------------------------------
// Kernel 3: causal attention v3 — parallel no-max flash [UNCHANGED from R11,
// isolate proj change this round]
// ---------------------------------------------------------------------------
__global__ __launch_bounds__(256) void attn_kernel(
    const unsigned short* __restrict__ qs, const unsigned short* __restrict__ ks,
    const unsigned short* __restrict__ vT, float* __restrict__ out) {
    __shared__ unsigned short Kl[4 * 64 * 72];
    __shared__ unsigned short Vl[64 * 264];
    __shared__ unsigned short P[4][16 * 72];
    __shared__ float Ll[4][16];
    float* Of = (float*)Kl;  // merge buffer aliases Kl: [4][16][68] fp32

    const int tid  = threadIdx.x;
    const int lane = tid & 63;
    const int wave = tid >> 6;
    const int quad = lane >> 4;
    const int l16  = lane & 15;
    const int bx   = blockIdx.x;
    const int b    = bx & 7;
    const int i    = bx >> 3;
    const int qt   = (i & 1) ? (127 - (i >> 1)) : (i >> 1);
    const int t0   = qt * 16;

    const unsigned short* qb = qs + (size_t)b * 131072;
    const unsigned short* kb = ks + (size_t)b * 131072;
    const unsigned short* vb = vT + (size_t)b * 131072;

    const int ksr = tid >> 3;
    const int ksc = (tid & 7) * 8;
    const int vsr = tid >> 5;
    const int vsc = (tid & 31) * 8;

    const int qrow = t0 + l16;
    const short8 qf0 = *(const short8*)(qb + (size_t)qrow * 64 + quad * 8);
    const short8 qf1 = *(const short8*)(qb + (size_t)qrow * 64 + 32 + quad * 8);

    float4v o[4];
#pragma unroll
    for (int ot = 0; ot < 4; ot++) o[ot] = (float4v){0.f, 0.f, 0.f, 0.f};
    float lpart = 0.f;

    const int nkb  = (qt >> 2) + 1;
    const int nsup = (nkb + 3) >> 2;

    for (int s = 0; s < nsup; s++) {
        const int key0 = s * 256;
        __syncthreads();
#pragma unroll
        for (int i2 = 0; i2 < 8; i2++) {
            int kr = key0 + i2 * 32 + ksr; kr = kr < 2047 ? kr : 2047;
            *(short8*)&Kl[(i2 * 32 + ksr) * 72 + ksc] = *(const short8*)(kb + (size_t)kr * 64 + ksc);
        }
#pragma unroll
        for (int i2 = 0; i2 < 8; i2++) {
            const int orow = i2 * 8 + vsr;
            int kc2 = key0 + vsc; kc2 = kc2 < 2040 ? kc2 : 2040;
            *(short8*)&Vl[orow * 264 + vsc] = *(const short8*)(vb + (size_t)orow * 2048 + kc2);
        }
        __syncthreads();

        const int jt = s * 4 + wave;
        if (jt < nkb) {
            const int kbase = wave * 64;
            float4v sv[4];
#pragma unroll
            for (int kt = 0; kt < 4; kt++) {
                const short8 ka = *(const short8*)&Kl[(kbase + kt * 16 + l16) * 72 + quad * 8];
                const short8 kc = *(const short8*)&Kl[(kbase + kt * 16 + l16) * 72 + 32 + quad * 8];
                float4v z = (float4v){0.f, 0.f, 0.f, 0.f};
                z = __builtin_amdgcn_mfma_f32_16x16x32_bf16(ka, qf0, z, 0, 0, 0);
                sv[kt] = __builtin_amdgcn_mfma_f32_16x16x32_bf16(kc, qf1, z, 0, 0, 0);
            }
            if (jt == nkb - 1) {
#pragma unroll
                for (int kt = 0; kt < 4; kt++)
#pragma unroll
                    for (int r = 0; r < 4; r++)
                        if (jt * 64 + kt * 16 + quad * 4 + r > qrow) sv[kt][r] = -1e30f;
            }
#pragma unroll
            for (int kt = 0; kt < 4; kt++) {
                float p0 = exp2f(sv[kt][0] * LOG2E);
                float p1 = exp2f(sv[kt][1] * LOG2E);
                float p2 = exp2f(sv[kt][2] * LOG2E);
                float p3 = exp2f(sv[kt][3] * LOG2E);
                lpart += (p0 + p1) + (p2 + p3);
                unsigned int lo = (unsigned int)f2bf(p0) | ((unsigned int)f2bf(p1) << 16);
                unsigned int hi = (unsigned int)f2bf(p2) | ((unsigned int)f2bf(p3) << 16);
                unsigned long long w = ((unsigned long long)hi << 32) | lo;
                *(unsigned long long*)&P[wave][l16 * 72 + kt * 16 + quad * 4] = w;
            }
#pragma unroll
            for (int kc = 0; kc < 2; kc++) {
                const short8 pf = *(const short8*)&P[wave][l16 * 72 + kc * 32 + quad * 8];
#pragma unroll
                for (int ot = 0; ot < 4; ot++) {
                    const short8 vf = *(const short8*)&Vl[(ot * 16 + l16) * 264 + wave * 64 + kc * 32 + quad * 8];
                    o[ot] = __builtin_amdgcn_mfma_f32_16x16x32_bf16(pf, vf, o[ot], 0, 0, 0);
                }
            }
        }
    }

    lpart += __shfl_xor(lpart, 16);
    lpart += __shfl_xor(lpart, 32);
    __syncthreads();
#pragma unroll
    for (int r = 0; r < 4; r++)
#pragma unroll
        for (int ot = 0; ot < 4; ot++)
            Of[wave * 1088 + (quad * 4 + r) * 68 + ot * 16 + l16] = o[ot][r];
    if (lane < 16) Ll[wave][lane] = lpart;
    __syncthreads();

    {
        const int row = tid >> 4;
        const int c0  = (tid & 15) * 4;
        const float lsum = Ll[0][row] + Ll[1][row] + Ll[2][row] + Ll[3][row];
        float4v v0 = *(const float4v*)&Of[0 * 1088 + row * 68 + c0];
        float4v v1 = *(const float4v*)&Of[1 * 1088 + row * 68 + c0];
        float4v v2 = *(const float4v*)&Of[2 * 1088 + row * 68 + c0];
        float4v v3 = *(const float4v*)&Of[3 * 1088 + row * 68 + c0];
        float4v res;
        const float inv = 1.0f / lsum;
#pragma unroll
        for (int j = 0; j < 4; j++)
            res[j] = ((v0[j] + v1[j]) + (v2[j] + v3[j])) * inv;
        float* ob = out + (size_t)b * 131072 + (size_t)(t0 + row) * 64 + c0;
        *(float4v*)ob = res;
    }
}

// ---------------------------------------------------------------------------
extern "C" void kernel_launch(void* const* d_in, const int* in_sizes, int n_in,
                              void* d_out, int out_size, void* d_ws, size_t ws_size,
                              hipStream_t stream) {
    const float* x  = (const float*)d_in[0];
    const float* Wk = (const float*)d_in[1];
    const float* Wq = (const float*)d_in[2];
    const float* Wv = (const float*)d_in[3];
    float* out = (float*)d_out;

    // Workspace: Wb 384 KB (+pad) | qs 2 MB | ks 2 MB | vT 2 MB
    unsigned short* Wb  = (unsigned short*)d_ws;
    unsigned short* qsb = (unsigned short*)((char*)d_ws + 393216);
    unsigned short* ksb = qsb + 1048576;
    unsigned short* vTb = ksb + 1048576;

    hipLaunchKernelGGL(wconv_kernel, dim3(768), dim3(256), 0, stream, Wk, Wq, Wv, Wb);
    hipLaunchKernelGGL(proj_kernel, dim3(1024), dim3(256), 0, stream, x, Wb, qsb, ksb, vTb);
    hipLaunchKernelGGL(attn_kernel, dim3(1024), dim3(256), 0, stream, qsb, ksb, vTb, out);
}

// Round 2
// 149.972 us; speedup vs baseline: 1.3034x; 1.3034x over previous
//
#include <hip/hip_runtime.h>
#include <hip/hip_bf16.h>

typedef __attribute__((ext_vector_type(8))) short short8;
typedef __attribute__((ext_vector_type(4))) float float4v;

#define LOG2E 1.44269504088896340736f

typedef __attribute__((address_space(1))) const unsigned int gu32;
typedef __attribute__((address_space(3))) unsigned int su32;

__device__ __forceinline__ unsigned short f2bf(float f) {
    unsigned int u = __float_as_uint(f);
    unsigned int r = (u + 0x7fffu + ((u >> 16) & 1u)) >> 16;  // RNE
    return (unsigned short)r;
}

// ---------------------------------------------------------------------------
// Kernel 1: convert Wk|Wq|Wv (fp32) -> combined bf16 Wb[192][1024]
// ---------------------------------------------------------------------------
__global__ void wconv_kernel(const float* __restrict__ Wk, const float* __restrict__ Wq,
                             const float* __restrict__ Wv, unsigned short* __restrict__ Wb) {
    int i = blockIdx.x * 256 + threadIdx.x;
    if (i >= 192 * 1024) return;
    float v;
    if (i < 65536)       v = Wk[i];
    else if (i < 131072) v = Wq[i - 65536];
    else                 v = Wv[i - 131072];
    Wb[i] = f2bf(v);
}

// ---------------------------------------------------------------------------
// Kernel 2: projection GEMM — round-13: R11 structure + COUNTED VMCNT (T4).
// R12 post-mortem: barrier-free direct-global version collapsed to 32 VGPR
// (compiler sank the prefetch loads to their uses -> serial latency chain,
// 84us). Revert to R11's staged global_load_lds structure (42us) and remove
// its real bottleneck: __syncthreads() drained vmcnt(0) every iteration, so
// stage loads had ~0 cycles in flight. Now: s_waitcnt vmcnt(4) + raw
// s_barrier -> next tile's 6 stage loads stay in flight across the barrier
// and fly under the current tile's 12 MFMAs (~450cy cover vs L2 ~200cy).
// A-register prefetch deepened to 2 tiles (~900cy cover vs L3 x-reads).
// vmcnt counting relies on per-iter issue order [6 stage][4 A-loads]; an
// empty asm memory clobber pins that split; sched_barrier(0) at iter top
// stops MFMA sinking across the barrier (rule #18). Tail: no wrap staging
// (avoids dangling LDS-DMA at endpgm); final iter drains vmcnt(0).
// WAR safety: STAGE(kt+1) overwrites the buffer last READ at iter kt-1;
// the barrier at iter kt top orders all waves' reads before the overwrite.
// ---------------------------------------------------------------------------
__global__ __launch_bounds__(256) void proj_kernel(
    const float* __restrict__ x, const unsigned short* __restrict__ Wb,
    unsigned short* __restrict__ qs, unsigned short* __restrict__ ks,
    unsigned short* __restrict__ vT) {
    __shared__ unsigned short Bl[2][12288];  // 2 x 192 rows x 64 ushort, 48 KB

    const int tid  = threadIdx.x;
    const int lane = tid & 63;
    const int wave = tid >> 6;
    const int rg   = wave & 1;   // row group
    const int g    = wave >> 1;  // n-tile group
    const int quad = lane >> 4;
    const int l16  = lane & 15;
    const int t0   = blockIdx.x * 32;

    // async staging geometry: wave covers regions wave*6..+5; region = 8 rows
    // of 128 B; lane l -> (row l>>3, LDS chunk l&7), source chunk (l&7)^(l>>3)
    const int srow_in = lane >> 3;                 // 0..7
    const int csrc    = (lane & 7) ^ srow_in;      // XOR swizzle source chunk

    const int rowA = t0 + rg * 16 + l16;
    const float* xr = x + (size_t)rowA * 1024;

    float4v acc[6];
#pragma unroll
    for (int n = 0; n < 6; n++) acc[n] = (float4v){0.f, 0.f, 0.f, 0.f};

#define STAGE_B(BUF, KN)                                                          \
    {                                                                             \
        _Pragma("unroll")                                                         \
        for (int i = 0; i < 6; i++) {                                             \
            const int region = wave * 6 + i;                                      \
            const int rowg   = region * 8 + srow_in;                              \
            const unsigned short* src = Wb + (size_t)rowg * 1024 + (KN) + csrc * 8; \
            __builtin_amdgcn_global_load_lds((gu32*)src,                          \
                                             (su32*)&Bl[BUF][region * 512],       \
                                             16, 0, 0);                           \
        }                                                                         \
    }

    // prologue: stage tile 0; A-register prefetch tiles 0 and 1 (2-deep)
    STAGE_B(0, 0)
    float4v a0[4], a1[4];
    a0[0] = *(const float4v*)(xr + quad * 8);
    a0[1] = *(const float4v*)(xr + quad * 8 + 4);
    a0[2] = *(const float4v*)(xr + 32 + quad * 8);
    a0[3] = *(const float4v*)(xr + 32 + quad * 8 + 4);
    a1[0] = *(const float4v*)(xr + 64 + quad * 8);
    a1[1] = *(const float4v*)(xr + 64 + quad * 8 + 4);
    a1[2] = *(const float4v*)(xr + 96 + quad * 8);
    a1[3] = *(const float4v*)(xr + 96 + quad * 8 + 4);

    const int swz = l16 & 7;

#pragma unroll
    for (int kt = 0; kt < 16; kt++) {
        __builtin_amdgcn_sched_barrier(0);
        // wait: stage(kt) + aload(kt) landed; newest 4 = aload(kt+1) may fly.
        if (kt < 15) {
            asm volatile("s_waitcnt vmcnt(4)" ::: "memory");
        } else {
            asm volatile("s_waitcnt vmcnt(0)" ::: "memory");
        }
        __builtin_amdgcn_s_barrier();
        if (kt < 15) STAGE_B((kt + 1) & 1, (kt + 1) * 64)
        asm volatile("" ::: "memory");  // pin issue order: stages before A-loads
        float4v an[4];
        if (kt < 14) {
            const int kn2 = (kt + 2) * 64;
            an[0] = *(const float4v*)(xr + kn2 + quad * 8);
            an[1] = *(const float4v*)(xr + kn2 + quad * 8 + 4);
            an[2] = *(const float4v*)(xr + kn2 + 32 + quad * 8);
            an[3] = *(const float4v*)(xr + kn2 + 32 + quad * 8 + 4);
        }
        const unsigned short* Bc = Bl[kt & 1];
#pragma unroll
        for (int kc = 0; kc < 2; kc++) {
            short8 af;
#pragma unroll
            for (int j = 0; j < 4; j++) af[j] = (short)f2bf(a0[kc * 2][j]);
#pragma unroll
            for (int j = 0; j < 4; j++) af[4 + j] = (short)f2bf(a0[kc * 2 + 1][j]);
#pragma unroll
            for (int n = 0; n < 6; n++) {
                const int row  = (g * 6 + n) * 16 + l16;
                const int coff = ((kc * 4 + quad) ^ swz) * 8;
                const short8 bf = *(const short8*)&Bc[row * 64 + coff];
                acc[n] = __builtin_amdgcn_mfma_f32_16x16x32_bf16(af, bf, acc[n], 0, 0, 0);
            }
        }
        if (kt < 14) {
#pragma unroll
            for (int i = 0; i < 4; i++) { a0[i] = a1[i]; a1[i] = an[i]; }
        } else if (kt < 15) {
#pragma unroll
            for (int i = 0; i < 4; i++) a0[i] = a1[i];
        }
    }
#undef STAGE_B

    // Epilogue. C layout: row = quad*4 + r, col = l16.
    const int rowD = t0 + rg * 16 + quad * 4;
#pragma unroll
    for (int r = 0; r < 4; r++) {
        const int t = rowD + r;
        const int b = t >> 11, tt = t & 2047;
        if (g == 0) {
#pragma unroll
            for (int n = 0; n < 4; n++)
                ks[(size_t)t * 64 + n * 16 + l16] = f2bf(acc[n][r]);
#pragma unroll
            for (int n = 4; n < 6; n++)
                qs[(size_t)t * 64 + (n - 4) * 16 + l16] = f2bf(acc[n][r] * 0.125f);
        } else {
#pragma unroll
            for (int n = 0; n < 2; n++)
                qs[(size_t)t * 64 + (n + 2) * 16 + l16] = f2bf(acc[n][r] * 0.125f);
#pragma unroll
            for (int n = 2; n < 6; n++)
                vT[(size_t)b * 131072 + (size_t)((n - 2) * 16 + l16) * 2048 + tt] = f2bf(acc[n][r]);
        }
    }
}

// ---------------------------------------------------------------------------
// Kernel 3: causal attention v3 — parallel no-max flash [UNCHANGED,
// isolate proj change this round]
// ---------------------------------------------------------------------------
__global__ __launch_bounds__(256) void attn_kernel(
    const unsigned short* __restrict__ qs, const unsigned short* __restrict__ ks,
    const unsigned short* __restrict__ vT, float* __restrict__ out) {
    __shared__ unsigned short Kl[4 * 64 * 72];
    __shared__ unsigned short Vl[64 * 264];
    __shared__ unsigned short P[4][16 * 72];
    __shared__ float Ll[4][16];
    float* Of = (float*)Kl;  // merge buffer aliases Kl: [4][16][68] fp32

    const int tid  = threadIdx.x;
    const int lane = tid & 63;
    const int wave = tid >> 6;
    const int quad = lane >> 4;
    const int l16  = lane & 15;
    const int bx   = blockIdx.x;
    const int b    = bx & 7;
    const int i    = bx >> 3;
    const int qt   = (i & 1) ? (127 - (i >> 1)) : (i >> 1);
    const int t0   = qt * 16;

    const unsigned short* qb = qs + (size_t)b * 131072;
    const unsigned short* kb = ks + (size_t)b * 131072;
    const unsigned short* vb = vT + (size_t)b * 131072;

    const int ksr = tid >> 3;
    const int ksc = (tid & 7) * 8;
    const int vsr = tid >> 5;
    const int vsc = (tid & 31) * 8;

    const int qrow = t0 + l16;
    const short8 qf0 = *(const short8*)(qb + (size_t)qrow * 64 + quad * 8);
    const short8 qf1 = *(const short8*)(qb + (size_t)qrow * 64 + 32 + quad * 8);

    float4v o[4];
#pragma unroll
    for (int ot = 0; ot < 4; ot++) o[ot] = (float4v){0.f, 0.f, 0.f, 0.f};
    float lpart = 0.f;

    const int nkb  = (qt >> 2) + 1;
    const int nsup = (nkb + 3) >> 2;

    for (int s = 0; s < nsup; s++) {
        const int key0 = s * 256;
        __syncthreads();
#pragma unroll
        for (int i2 = 0; i2 < 8; i2++) {
            int kr = key0 + i2 * 32 + ksr; kr = kr < 2047 ? kr : 2047;
            *(short8*)&Kl[(i2 * 32 + ksr) * 72 + ksc] = *(const short8*)(kb + (size_t)kr * 64 + ksc);
        }
#pragma unroll
        for (int i2 = 0; i2 < 8; i2++) {
            const int orow = i2 * 8 + vsr;
            int kc2 = key0 + vsc; kc2 = kc2 < 2040 ? kc2 : 2040;
            *(short8*)&Vl[orow * 264 + vsc] = *(const short8*)(vb + (size_t)orow * 2048 + kc2);
        }
        __syncthreads();

        const int jt = s * 4 + wave;
        if (jt < nkb) {
            const int kbase = wave * 64;
            float4v sv[4];
#pragma unroll
            for (int kt = 0; kt < 4; kt++) {
                const short8 ka = *(const short8*)&Kl[(kbase + kt * 16 + l16) * 72 + quad * 8];
                const short8 kc = *(const short8*)&Kl[(kbase + kt * 16 + l16) * 72 + 32 + quad * 8];
                float4v z = (float4v){0.f, 0.f, 0.f, 0.f};
                z = __builtin_amdgcn_mfma_f32_16x16x32_bf16(ka, qf0, z, 0, 0, 0);
                sv[kt] = __builtin_amdgcn_mfma_f32_16x16x32_bf16(kc, qf1, z, 0, 0, 0);
            }
            if (jt == nkb - 1) {
#pragma unroll
                for (int kt = 0; kt < 4; kt++)
#pragma unroll
                    for (int r = 0; r < 4; r++)
                        if (jt * 64 + kt * 16 + quad * 4 + r > qrow) sv[kt][r] = -1e30f;
            }
#pragma unroll
            for (int kt = 0; kt < 4; kt++) {
                float p0 = exp2f(sv[kt][0] * LOG2E);
                float p1 = exp2f(sv[kt][1] * LOG2E);
                float p2 = exp2f(sv[kt][2] * LOG2E);
                float p3 = exp2f(sv[kt][3] * LOG2E);
                lpart += (p0 + p1) + (p2 + p3);
                unsigned int lo = (unsigned int)f2bf(p0) | ((unsigned int)f2bf(p1) << 16);
                unsigned int hi = (unsigned int)f2bf(p2) | ((unsigned int)f2bf(p3) << 16);
                unsigned long long w = ((unsigned long long)hi << 32) | lo;
                *(unsigned long long*)&P[wave][l16 * 72 + kt * 16 + quad * 4] = w;
            }
#pragma unroll
            for (int kc = 0; kc < 2; kc++) {
                const short8 pf = *(const short8*)&P[wave][l16 * 72 + kc * 32 + quad * 8];
#pragma unroll
                for (int ot = 0; ot < 4; ot++) {
                    const short8 vf = *(const short8*)&Vl[(ot * 16 + l16) * 264 + wave * 64 + kc * 32 + quad * 8];
                    o[ot] = __builtin_amdgcn_mfma_f32_16x16x32_bf16(pf, vf, o[ot], 0, 0, 0);
                }
            }
        }
    }

    lpart += __shfl_xor(lpart, 16);
    lpart += __shfl_xor(lpart, 32);
    __syncthreads();
#pragma unroll
    for (int r = 0; r < 4; r++)
#pragma unroll
        for (int ot = 0; ot < 4; ot++)
            Of[wave * 1088 + (quad * 4 + r) * 68 + ot * 16 + l16] = o[ot][r];
    if (lane < 16) Ll[wave][lane] = lpart;
    __syncthreads();

    {
        const int row = tid >> 4;
        const int c0  = (tid & 15) * 4;
        const float lsum = Ll[0][row] + Ll[1][row] + Ll[2][row] + Ll[3][row];
        float4v v0 = *(const float4v*)&Of[0 * 1088 + row * 68 + c0];
        float4v v1 = *(const float4v*)&Of[1 * 1088 + row * 68 + c0];
        float4v v2 = *(const float4v*)&Of[2 * 1088 + row * 68 + c0];
        float4v v3 = *(const float4v*)&Of[3 * 1088 + row * 68 + c0];
        float4v res;
        const float inv = 1.0f / lsum;
#pragma unroll
        for (int j = 0; j < 4; j++)
            res[j] = ((v0[j] + v1[j]) + (v2[j] + v3[j])) * inv;
        float* ob = out + (size_t)b * 131072 + (size_t)(t0 + row) * 64 + c0;
        *(float4v*)ob = res;
    }
}

// ---------------------------------------------------------------------------
extern "C" void kernel_launch(void* const* d_in, const int* in_sizes, int n_in,
                              void* d_out, int out_size, void* d_ws, size_t ws_size,
                              hipStream_t stream) {
    const float* x  = (const float*)d_in[0];
    const float* Wk = (const float*)d_in[1];
    const float* Wq = (const float*)d_in[2];
    const float* Wv = (const float*)d_in[3];
    float* out = (float*)d_out;

    // Workspace: Wb 384 KB (+pad) | qs 2 MB | ks 2 MB | vT 2 MB
    unsigned short* Wb  = (unsigned short*)d_ws;
    unsigned short* qsb = (unsigned short*)((char*)d_ws + 393216);
    unsigned short* ksb = qsb + 1048576;
    unsigned short* vTb = ksb + 1048576;

    hipLaunchKernelGGL(wconv_kernel, dim3(768), dim3(256), 0, stream, Wk, Wq, Wv, Wb);
    hipLaunchKernelGGL(proj_kernel, dim3(512), dim3(256), 0, stream, x, Wb, qsb, ksb, vTb);
    hipLaunchKernelGGL(attn_kernel, dim3(1024), dim3(256), 0, stream, qsb, ksb, vTb, out);
}